// Round 1
// baseline (59.876 us; speedup 1.0000x reference)
//
#include <hip/hip_runtime.h>
#include <math.h>

// HyperConnections: out[(b*S+t), n, d] = sum_s M[t][s] * in[(b*S+s), n, d]
// M[t][s] = sinkhorn(H_res/tau)[s][t] + softmax(H_post)[t] * softmax(H_pre)[s]
//
// B=4, S=4, N=2048, D=1024, fp32. Memory-bound: 128 MiB in + 128 MiB out.

#define HC_S 4
#define HC_TAU 0.05f
#define HC_ITERS 10

// N*D/4 float4 elements per stream = 2048*1024/4 = 524288 = 2^19
constexpr int ND4 = (2048 * 1024) / 4;
constexpr int ND4_SHIFT = 19;
constexpr int TOTAL = 4 * ND4; // B * ND4 work items (each covers all 4 streams)

__device__ inline float lse4(float a, float b, float c, float d) {
    float m = fmaxf(fmaxf(a, b), fmaxf(c, d));
    return m + logf(expf(a - m) + expf(b - m) + expf(c - m) + expf(d - m));
}

__global__ __launch_bounds__(256) void hc_mix_kernel(
    const float4* __restrict__ in, float4* __restrict__ out,
    const float* __restrict__ Hres, const float* __restrict__ Hpre,
    const float* __restrict__ Hpost)
{
    __shared__ float Ms[16];

    if (threadIdx.x == 0) {
        // --- log-domain Sinkhorn on 4x4 (10 iters, tau=0.05) ---
        float Z[HC_S][HC_S], u[HC_S], v[HC_S];
        #pragma unroll
        for (int i = 0; i < HC_S; ++i) { u[i] = 0.f; v[i] = 0.f; }
        #pragma unroll
        for (int i = 0; i < HC_S; ++i)
            #pragma unroll
            for (int j = 0; j < HC_S; ++j)
                Z[i][j] = Hres[i * HC_S + j] * (1.0f / HC_TAU);

        for (int it = 0; it < HC_ITERS; ++it) {
            #pragma unroll
            for (int i = 0; i < HC_S; ++i)
                u[i] = -lse4(Z[i][0] + v[0], Z[i][1] + v[1],
                             Z[i][2] + v[2], Z[i][3] + v[3]);
            #pragma unroll
            for (int j = 0; j < HC_S; ++j)
                v[j] = -lse4(Z[0][j] + u[0], Z[1][j] + u[1],
                             Z[2][j] + u[2], Z[3][j] + u[3]);
        }

        // --- softmax(H_pre), softmax(H_post) ---
        float hp[HC_S];
        float m = fmaxf(fmaxf(Hpre[0], Hpre[1]), fmaxf(Hpre[2], Hpre[3]));
        float ssum = 0.f;
        #pragma unroll
        for (int s = 0; s < HC_S; ++s) { hp[s] = expf(Hpre[s] - m); ssum += hp[s]; }
        float inv = 1.0f / ssum;
        #pragma unroll
        for (int s = 0; s < HC_S; ++s) hp[s] *= inv;

        float bt[HC_S];
        m = fmaxf(fmaxf(Hpost[0], Hpost[1]), fmaxf(Hpost[2], Hpost[3]));
        ssum = 0.f;
        #pragma unroll
        for (int t = 0; t < HC_S; ++t) { bt[t] = expf(Hpost[t] - m); ssum += bt[t]; }
        inv = 1.0f / ssum;
        #pragma unroll
        for (int t = 0; t < HC_S; ++t) bt[t] *= inv;

        // M[t][s] = h_res[s][t] + beta[t] * h_pre[s];  h_res[s][t] = exp(Z[s][t]+u[s]+v[t])
        #pragma unroll
        for (int t = 0; t < HC_S; ++t)
            #pragma unroll
            for (int s = 0; s < HC_S; ++s)
                Ms[t * HC_S + s] = expf(Z[s][t] + u[s] + v[t]) + bt[t] * hp[s];
    }
    __syncthreads();

    float M[16];
    #pragma unroll
    for (int k = 0; k < 16; ++k) M[k] = Ms[k];

    // --- grid-stride mix: 4 stream loads -> 4 stream stores, float4 each ---
    for (int i = blockIdx.x * blockDim.x + threadIdx.x; i < TOTAL;
         i += gridDim.x * blockDim.x) {
        int b = i >> ND4_SHIFT;          // batch index
        int r = i & (ND4 - 1);           // position within (n,d) plane
        size_t base = ((size_t)(b * 4) << ND4_SHIFT) + (size_t)r;

        float4 v0 = in[base];
        float4 v1 = in[base + ND4];
        float4 v2 = in[base + 2 * ND4];
        float4 v3 = in[base + 3 * ND4];

        #pragma unroll
        for (int t = 0; t < 4; ++t) {
            float4 o;
            o.x = M[4*t+0] * v0.x + M[4*t+1] * v1.x + M[4*t+2] * v2.x + M[4*t+3] * v3.x;
            o.y = M[4*t+0] * v0.y + M[4*t+1] * v1.y + M[4*t+2] * v2.y + M[4*t+3] * v3.y;
            o.z = M[4*t+0] * v0.z + M[4*t+1] * v1.z + M[4*t+2] * v2.z + M[4*t+3] * v3.z;
            o.w = M[4*t+0] * v0.w + M[4*t+1] * v1.w + M[4*t+2] * v2.w + M[4*t+3] * v3.w;
            out[base + (size_t)t * ND4] = o;
        }
    }
}

extern "C" void kernel_launch(void* const* d_in, const int* in_sizes, int n_in,
                              void* d_out, int out_size, void* d_ws, size_t ws_size,
                              hipStream_t stream) {
    const float4* in   = (const float4*)d_in[0];
    const float* Hres  = (const float*)d_in[1];
    const float* Hpre  = (const float*)d_in[2];
    const float* Hpost = (const float*)d_in[3];
    float4* out = (float4*)d_out;

    // 2048 blocks x 256 threads: 4 grid-stride iterations per thread.
    hc_mix_kernel<<<2048, 256, 0, stream>>>(in, out, Hres, Hpre, Hpost);
}